// Round 7
// baseline (10610.593 us; speedup 1.0000x reference)
//
#include <hip/hip_runtime.h>
#include <stdint.h>

#define N_B 32
#define T_S 2048
#define H_D 1024
#define HSLOT ((size_t)N_B * H_D)   // one parity slot: 32 x 1024 packets

// One DPP f32 add-reduce step: x += dpp(x) on enabled rows.
template<int CTRL, int ROWMASK>
__device__ __forceinline__ float dpp_add(float x) {
    int t = __builtin_amdgcn_update_dpp(0, __builtin_bit_cast(int, x),
                                        CTRL, ROWMASK, 0xf, true);
    return x + __builtin_bit_cast(float, t);
}

// Spin until packet tag matches `want`. Relaxed atomic loads, with a periodic
// RMW (executes at the coherence point) as livelock insurance.
__device__ __forceinline__ unsigned long long wait_pkt(unsigned long long* a,
                                                       unsigned want,
                                                       unsigned long long v) {
    int spins = 0;
    while ((unsigned)(v >> 32) != want) {
        if ((++spins & 63) == 0)
            v = __hip_atomic_fetch_or(a, 0ull, __ATOMIC_RELAXED, __HIP_MEMORY_SCOPE_AGENT);
        else
            v = __hip_atomic_load(a, __ATOMIC_RELAXED, __HIP_MEMORY_SCOPE_AGENT);
    }
    return v;
}

// fast tanh: clamp + v_exp_f32 + v_rcp_f32;  |err| ~1e-6, threshold 1.3e-2
__device__ __forceinline__ float fast_tanh(float x) {
    float xc = fminf(fmaxf(x, -10.0f), 10.0f);
    float e  = __builtin_amdgcn_exp2f(xc * 2.885390081777927f);  // e^{2x}
    return (e - 1.0f) * __builtin_amdgcn_rcpf(e + 1.0f);
}

// Persistent RNN kernel — W lives in LDS (allocator-proof; rounds 2-6 proved
// the register allocator remats (r2-4) or scratch-spills (r6) a register W).
//
// Grid: 256 blocks x 512 threads. Block -> (group g of 4 batches, slice s of
// 32 cols). g = blk&7: all 32 blocks of a group share one XCD under
// round-robin dispatch, so the h packet exchange stays in that XCD's L2.
//
// LDS W layout (conflict-free by construction):
//   wlds[row*8 + (chunk ^ (row&7))], chunk = 16B float4 of 4 cols.
//   Read (fixed wv, lanes rc): bank = ((wv^(rc&7))*4)%32 -> each 8-lane group
//   covers all 32 banks exactly once. Same argument for the staging writes.
// h layout: two float2 planes h2[pair][row] ({b0,b1},{b2,b3}): 8B/lane
//   stride -> 2-way aliasing = free (m136). (Round 5's [row][4] float4 layout
//   was the 8-way-conflict mistake.)
__global__ __launch_bounds__(512, 1) void rnn_persist(
    const int* __restrict__ xx, const float* __restrict__ embed,
    const float* __restrict__ W, const float* __restrict__ bh,
    float* __restrict__ out, unsigned long long* __restrict__ hbuf)
{
    __shared__ float4 wlds[8192];      // W slice 1024x32 fp32, swizzled, 128 KB
    __shared__ float2 h2[2][1024];     // h planes: [pair][row], 16 KB
    __shared__ float  xh_lds[4][32];   // embed slice for current step

    const int tid = threadIdx.x;
    const int blk = blockIdx.x;
    const int g  = blk & 7;            // group (XCD-local comm)
    const int s  = blk >> 3;           // col slice 0..31
    const int n0 = g * 4;
    const int wv = tid >> 6;           // wave id: col chunk (4 cols)
    const int rc = tid & 63;           // lane: row chunk
    const int c_base = s * 32 + wv * 4;
    const int chunk  = wv ^ (rc & 7);  // swizzled W chunk for GEMV reads

    // ---- one-time: stage W slice into LDS, swizzled, coalesced ----
    {
        int r0 = tid >> 3, c = tid & 7;    // 8 chunks per row
        for (int i = 0; i < 16; ++i) {
            int row = r0 + i * 64;
            float4 v = *(const float4*)(W + (size_t)row * H_D + s * 32 + c * 4);
            wlds[row * 8 + (c ^ (row & 7))] = v;
        }
    }
    for (int e = tid; e < 1024; e += 512) {
        h2[0][e] = float2{0.0f, 0.0f};     // h_0 = 0
        h2[1][e] = float2{0.0f, 0.0f};
    }
    __syncthreads();

    // lanes 48..63 of each wave own its 16 outputs (4 batches x 4 cols)
    const int o  = rc - 48;
    const int ob = (o >> 2) & 3, oj = o & 3;
    int my_n = 0, my_c = 0, xh_i = 0; float my_bias = 0.0f;
    if (o >= 0) {
        my_c    = c_base + oj;
        my_n    = n0 + ob;
        my_bias = bh[my_c];
        xh_i    = ob * 32 + (wv * 4 + oj);
    }

    // ---- embed prefetch chain (tokens read straight from global; tiny) ----
    // step t (1-based) uses token index t-1.
    float r_xh = 0.0f;   // embed value for the CURRENT step
    int   r_tok = 0;     // token for the NEXT step
    const int eb = tid >> 5, ec = tid & 31;      // batch, col (tid < 128)
    if (tid < 128) {
        int tok0 = xx[(size_t)(n0 + eb) * T_S + 0];
        r_xh  = embed[(size_t)tok0 * H_D + s * 32 + ec];
        r_tok = xx[(size_t)(n0 + eb) * T_S + 1];
    }

    for (int t = 1; t <= T_S; ++t) {
        if (tid < 128) {
            xh_lds[eb][ec] = r_xh;                       // for this step
            int tok = r_tok;                             // token idx t (next step)
            int ti  = t + 1 < T_S ? t + 1 : T_S - 1;
            r_tok = xx[(size_t)(n0 + eb) * T_S + ti];    // token idx t+1
            r_xh  = embed[(size_t)tok * H_D + s * 32 + ec];
        }
        // stage h_{t-1} from parity slot (t-1)&1  (t=1: h_0 already zeroed)
        if (t >= 2) {
            const unsigned tag = (unsigned)(t - 1);
            unsigned long long* base = hbuf + ((size_t)((t - 1) & 1)) * HSLOT;
            unsigned long long* a0 = base + (size_t)(n0 + 0) * H_D + tid;
            unsigned long long* a1 = base + (size_t)(n0 + 1) * H_D + tid;
            unsigned long long* a2 = base + (size_t)(n0 + 2) * H_D + tid;
            unsigned long long* a3 = base + (size_t)(n0 + 3) * H_D + tid;
            unsigned long long v0 = __hip_atomic_load(a0, __ATOMIC_RELAXED, __HIP_MEMORY_SCOPE_AGENT);
            unsigned long long v1 = __hip_atomic_load(a1, __ATOMIC_RELAXED, __HIP_MEMORY_SCOPE_AGENT);
            unsigned long long v2 = __hip_atomic_load(a2, __ATOMIC_RELAXED, __HIP_MEMORY_SCOPE_AGENT);
            unsigned long long v3 = __hip_atomic_load(a3, __ATOMIC_RELAXED, __HIP_MEMORY_SCOPE_AGENT);
            unsigned long long u0 = __hip_atomic_load(a0 + 512, __ATOMIC_RELAXED, __HIP_MEMORY_SCOPE_AGENT);
            unsigned long long u1 = __hip_atomic_load(a1 + 512, __ATOMIC_RELAXED, __HIP_MEMORY_SCOPE_AGENT);
            unsigned long long u2 = __hip_atomic_load(a2 + 512, __ATOMIC_RELAXED, __HIP_MEMORY_SCOPE_AGENT);
            unsigned long long u3 = __hip_atomic_load(a3 + 512, __ATOMIC_RELAXED, __HIP_MEMORY_SCOPE_AGENT);
            v0 = wait_pkt(a0, tag, v0);
            v1 = wait_pkt(a1, tag, v1);
            v2 = wait_pkt(a2, tag, v2);
            v3 = wait_pkt(a3, tag, v3);
            u0 = wait_pkt(a0 + 512, tag, u0);
            u1 = wait_pkt(a1 + 512, tag, u1);
            u2 = wait_pkt(a2 + 512, tag, u2);
            u3 = wait_pkt(a3 + 512, tag, u3);
            h2[0][tid]       = float2{ __builtin_bit_cast(float, (unsigned)v0),
                                       __builtin_bit_cast(float, (unsigned)v1) };
            h2[1][tid]       = float2{ __builtin_bit_cast(float, (unsigned)v2),
                                       __builtin_bit_cast(float, (unsigned)v3) };
            h2[0][tid + 512] = float2{ __builtin_bit_cast(float, (unsigned)u0),
                                       __builtin_bit_cast(float, (unsigned)u1) };
            h2[1][tid + 512] = float2{ __builtin_bit_cast(float, (unsigned)u2),
                                       __builtin_bit_cast(float, (unsigned)u3) };
        }
        __syncthreads();

        // partial GEMV: 16 rows x 4 cols x 4 batches; W streamed from LDS
        float acc[4][4];   // [batch][col], all indices compile-time
#pragma unroll
        for (int b = 0; b < 4; ++b)
#pragma unroll
            for (int j = 0; j < 4; ++j) acc[b][j] = 0.0f;
#pragma unroll
        for (int k = 0; k < 16; ++k) {
            const int row = k * 64 + rc;
            float4 w4  = wlds[row * 8 + chunk];
            float2 a01 = h2[0][row];
            float2 a23 = h2[1][row];
            const float wj[4] = { w4.x, w4.y, w4.z, w4.w };
#pragma unroll
            for (int j = 0; j < 4; ++j) {
                acc[0][j] = fmaf(a01.x, wj[j], acc[0][j]);
                acc[1][j] = fmaf(a01.y, wj[j], acc[1][j]);
                acc[2][j] = fmaf(a23.x, wj[j], acc[2][j]);
                acc[3][j] = fmaf(a23.y, wj[j], acc[3][j]);
            }
        }

        // 64-lane reduce of 16 values; totals land in lanes 48..63 (row 3)
        float outv = 0.0f;
#pragma unroll
        for (int oo = 0; oo < 16; ++oo) {
            float v = acc[oo >> 2][oo & 3];
            v = dpp_add<0xB1,  0xf>(v);   // quad_perm xor1
            v = dpp_add<0x4E,  0xf>(v);   // quad_perm xor2
            v = dpp_add<0x141, 0xf>(v);   // row_half_mirror -> sum of 8
            v = dpp_add<0x140, 0xf>(v);   // row_mirror      -> sum of 16
            v = dpp_add<0x142, 0xa>(v);   // row_bcast15 -> rows 1,3
            v = dpp_add<0x143, 0xc>(v);   // row_bcast31 -> row 3 = total
            if (o == oo) outv = v;
        }

        if (o >= 0) {
            float pre = outv + ((const float*)xh_lds)[xh_i] + my_bias;
            float hv  = fast_tanh(pre);
            // publish FIRST (consumer-visible store leads the critical path)
            unsigned long long p = ((unsigned long long)(unsigned)t << 32)
                                 | (unsigned long long)__builtin_bit_cast(unsigned, hv);
            __hip_atomic_store(hbuf + ((size_t)(t & 1)) * HSLOT + (size_t)my_n * H_D + my_c,
                               p, __ATOMIC_RELAXED, __HIP_MEMORY_SCOPE_AGENT);
            out[((size_t)my_n * T_S + (t - 1)) * H_D + my_c] = hv;
            if (t == T_S)
                out[(size_t)N_B * T_S * H_D + (size_t)my_n * H_D + my_c] = hv;
        }
        __syncthreads();   // h2/xh_lds may be overwritten next step
    }
}

extern "C" void kernel_launch(void* const* d_in, const int* in_sizes, int n_in,
                              void* d_out, int out_size, void* d_ws, size_t ws_size,
                              hipStream_t stream) {
    const int*   xx    = (const int*)d_in[0];
    const float* embed = (const float*)d_in[1];
    const float* W     = (const float*)d_in[2];
    const float* bh    = (const float*)d_in[3];
    float* out = (float*)d_out;
    unsigned long long* hbuf = (unsigned long long*)d_ws;

    // clear tags in BOTH parity slots each call (kills cross-replay stale-tag match)
    hipMemsetAsync(d_ws, 0, 2 * HSLOT * sizeof(unsigned long long), stream);

    void* args[] = { (void*)&xx, (void*)&embed, (void*)&W, (void*)&bh,
                     (void*)&out, (void*)&hbuf };
    hipLaunchCooperativeKernel((const void*)rnn_persist, dim3(256), dim3(512),
                               args, 0, stream);
}

// Round 8
// 10147.459 us; speedup vs baseline: 1.0456x; 1.0456x over previous
//
#include <hip/hip_runtime.h>
#include <stdint.h>

#define N_B 32
#define T_S 2048
#define H_D 1024
#define HSLOT ((size_t)N_B * H_D)   // one parity slot: 32 x 1024 packets

// One DPP f32 add-reduce step: x += dpp(x) on enabled rows.
template<int CTRL, int ROWMASK>
__device__ __forceinline__ float dpp_add(float x) {
    int t = __builtin_amdgcn_update_dpp(0, __builtin_bit_cast(int, x),
                                        CTRL, ROWMASK, 0xf, true);
    return x + __builtin_bit_cast(float, t);
}

// Spin until packet tag matches `want`. Relaxed atomic loads, with a periodic
// RMW (executes at the coherence point) as livelock insurance.
__device__ __forceinline__ unsigned long long wait_pkt(unsigned long long* a,
                                                       unsigned want,
                                                       unsigned long long v) {
    int spins = 0;
    while ((unsigned)(v >> 32) != want) {
        if ((++spins & 63) == 0)
            v = __hip_atomic_fetch_or(a, 0ull, __ATOMIC_RELAXED, __HIP_MEMORY_SCOPE_AGENT);
        else
            v = __hip_atomic_load(a, __ATOMIC_RELAXED, __HIP_MEMORY_SCOPE_AGENT);
    }
    return v;
}

// fast tanh: clamp + v_exp_f32 + v_rcp_f32;  |err| ~1e-6, threshold 1.3e-2
__device__ __forceinline__ float fast_tanh(float x) {
    float xc = fminf(fmaxf(x, -10.0f), 10.0f);
    float e  = __builtin_amdgcn_exp2f(xc * 2.885390081777927f);  // e^{2x}
    return (e - 1.0f) * __builtin_amdgcn_rcpf(e + 1.0f);
}

// Persistent RNN kernel — W in LDS, COLUMN-MAJOR, read with ds_read_b32.
//
// Grid: 256 blocks x 512 threads. Block -> (group g of 4 batches, slice s of
// 32 cols). g = blk&7: all 32 blocks of a group share one XCD under
// round-robin dispatch, so the h packet exchange stays in that XCD's L2.
//
// W LDS layout — provably conflict-free (no phase-group assumptions):
//   wlds[lc*1024 + row], read at row = k*64 + rc with fixed (lc,k) per instr.
//   bank = (lc*1024 + k*64 + rc) % 32 = rc % 32  (1024,64 ≡ 0 mod 32)
//   -> 64 lanes on 32 banks = exactly 2 lanes/bank = free [m136].
//   Round 7's float4+XOR layout measured 2.8e8 conflicts; b128 phase
//   grouping is not the 8-lane model — scalar b32 sidesteps it entirely.
//   All 64 reads/thread/step fold to ONE base VGPR + imm offsets (<16 KB).
// h layout: two float2 planes h2[pair][row] ({b0,b1},{b2,b3}); 4-way on 16
//   instrs/step — immaterial volume.
__global__ __launch_bounds__(512, 1) void rnn_persist(
    const int* __restrict__ xx, const float* __restrict__ embed,
    const float* __restrict__ W, const float* __restrict__ bh,
    float* __restrict__ out, unsigned long long* __restrict__ hbuf)
{
    __shared__ float  wlds[32 * 1024];   // W slice, col-major, 128 KB
    __shared__ float2 h2[2][1024];       // h planes: [pair][row], 16 KB
    __shared__ float  xh_lds[4][32];     // embed slice for current step

    const int tid = threadIdx.x;
    const int blk = blockIdx.x;
    const int g  = blk & 7;            // group (XCD-local comm)
    const int s  = blk >> 3;           // col slice 0..31
    const int n0 = g * 4;
    const int wv = tid >> 6;           // wave id: col chunk (4 cols)
    const int rc = tid & 63;           // lane: row chunk
    const int c_base = s * 32 + wv * 4;

    // ---- one-time: stage W slice into LDS, col-major ----
    {
        int r0 = tid >> 3, c4 = tid & 7;   // 8 threads per row, 4 cols each
        for (int i = 0; i < 16; ++i) {
            int row = r0 + i * 64;
            float4 v = *(const float4*)(W + (size_t)row * H_D + s * 32 + c4 * 4);
            wlds[(c4 * 4 + 0) * 1024 + row] = v.x;
            wlds[(c4 * 4 + 1) * 1024 + row] = v.y;
            wlds[(c4 * 4 + 2) * 1024 + row] = v.z;
            wlds[(c4 * 4 + 3) * 1024 + row] = v.w;
        }
    }
    for (int e = tid; e < 1024; e += 512) {
        h2[0][e] = float2{0.0f, 0.0f};     // h_0 = 0
        h2[1][e] = float2{0.0f, 0.0f};
    }
    __syncthreads();

    // lanes 48..63 of each wave own its 16 outputs (4 batches x 4 cols)
    const int o  = rc - 48;
    const int ob = (o >> 2) & 3, oj = o & 3;
    int my_n = 0, my_c = 0, xh_i = 0; float my_bias = 0.0f;
    if (o >= 0) {
        my_c    = c_base + oj;
        my_n    = n0 + ob;
        my_bias = bh[my_c];
        xh_i    = ob * 32 + (wv * 4 + oj);
    }

    // ---- embed prefetch chain ----
    float r_xh = 0.0f;   // embed value for the CURRENT step
    int   r_tok = 0;     // token for the NEXT step
    const int eb = tid >> 5, ec = tid & 31;      // batch, col (tid < 128)
    if (tid < 128) {
        int tok0 = xx[(size_t)(n0 + eb) * T_S + 0];
        r_xh  = embed[(size_t)tok0 * H_D + s * 32 + ec];
        r_tok = xx[(size_t)(n0 + eb) * T_S + 1];
    }

    // per-wave bases for the GEMV (all inner offsets are compile-time imms)
    const float*  wbase = &wlds[(wv * 4) * 1024 + rc];
    const float2* hb0   = &h2[0][rc];
    const float2* hb1   = &h2[1][rc];

    for (int t = 1; t <= T_S; ++t) {
        if (tid < 128) {
            xh_lds[eb][ec] = r_xh;
            int tok = r_tok;
            int ti  = t + 1 < T_S ? t + 1 : T_S - 1;
            r_tok = xx[(size_t)(n0 + eb) * T_S + ti];
            r_xh  = embed[(size_t)tok * H_D + s * 32 + ec];
        }
        // stage h_{t-1} from parity slot (t-1)&1  (t=1: h_0 already zeroed)
        if (t >= 2) {
            const unsigned tag = (unsigned)(t - 1);
            unsigned long long* base = hbuf + ((size_t)((t - 1) & 1)) * HSLOT;
            unsigned long long* a0 = base + (size_t)(n0 + 0) * H_D + tid;
            unsigned long long* a1 = base + (size_t)(n0 + 1) * H_D + tid;
            unsigned long long* a2 = base + (size_t)(n0 + 2) * H_D + tid;
            unsigned long long* a3 = base + (size_t)(n0 + 3) * H_D + tid;
            unsigned long long v0 = __hip_atomic_load(a0, __ATOMIC_RELAXED, __HIP_MEMORY_SCOPE_AGENT);
            unsigned long long v1 = __hip_atomic_load(a1, __ATOMIC_RELAXED, __HIP_MEMORY_SCOPE_AGENT);
            unsigned long long v2 = __hip_atomic_load(a2, __ATOMIC_RELAXED, __HIP_MEMORY_SCOPE_AGENT);
            unsigned long long v3 = __hip_atomic_load(a3, __ATOMIC_RELAXED, __HIP_MEMORY_SCOPE_AGENT);
            unsigned long long u0 = __hip_atomic_load(a0 + 512, __ATOMIC_RELAXED, __HIP_MEMORY_SCOPE_AGENT);
            unsigned long long u1 = __hip_atomic_load(a1 + 512, __ATOMIC_RELAXED, __HIP_MEMORY_SCOPE_AGENT);
            unsigned long long u2 = __hip_atomic_load(a2 + 512, __ATOMIC_RELAXED, __HIP_MEMORY_SCOPE_AGENT);
            unsigned long long u3 = __hip_atomic_load(a3 + 512, __ATOMIC_RELAXED, __HIP_MEMORY_SCOPE_AGENT);
            v0 = wait_pkt(a0, tag, v0);
            v1 = wait_pkt(a1, tag, v1);
            v2 = wait_pkt(a2, tag, v2);
            v3 = wait_pkt(a3, tag, v3);
            u0 = wait_pkt(a0 + 512, tag, u0);
            u1 = wait_pkt(a1 + 512, tag, u1);
            u2 = wait_pkt(a2 + 512, tag, u2);
            u3 = wait_pkt(a3 + 512, tag, u3);
            h2[0][tid]       = float2{ __builtin_bit_cast(float, (unsigned)v0),
                                       __builtin_bit_cast(float, (unsigned)v1) };
            h2[1][tid]       = float2{ __builtin_bit_cast(float, (unsigned)v2),
                                       __builtin_bit_cast(float, (unsigned)v3) };
            h2[0][tid + 512] = float2{ __builtin_bit_cast(float, (unsigned)u0),
                                       __builtin_bit_cast(float, (unsigned)u1) };
            h2[1][tid + 512] = float2{ __builtin_bit_cast(float, (unsigned)u2),
                                       __builtin_bit_cast(float, (unsigned)u3) };
        }
        __syncthreads();

        // partial GEMV: 16 rows x 4 cols x 4 batches; W streamed from LDS
        // (b32, bank = rc%32, 2-way = free; offsets are compile-time imms)
        float acc[4][4];   // [batch][col]
#pragma unroll
        for (int b = 0; b < 4; ++b)
#pragma unroll
            for (int j = 0; j < 4; ++j) acc[b][j] = 0.0f;
#pragma unroll
        for (int k = 0; k < 16; ++k) {
            float2 a01 = hb0[k * 64];
            float2 a23 = hb1[k * 64];
            float w0 = wbase[k * 64];
            float w1 = wbase[k * 64 + 1024];
            float w2 = wbase[k * 64 + 2048];
            float w3 = wbase[k * 64 + 3072];
            acc[0][0] = fmaf(a01.x, w0, acc[0][0]);
            acc[0][1] = fmaf(a01.x, w1, acc[0][1]);
            acc[0][2] = fmaf(a01.x, w2, acc[0][2]);
            acc[0][3] = fmaf(a01.x, w3, acc[0][3]);
            acc[1][0] = fmaf(a01.y, w0, acc[1][0]);
            acc[1][1] = fmaf(a01.y, w1, acc[1][1]);
            acc[1][2] = fmaf(a01.y, w2, acc[1][2]);
            acc[1][3] = fmaf(a01.y, w3, acc[1][3]);
            acc[2][0] = fmaf(a23.x, w0, acc[2][0]);
            acc[2][1] = fmaf(a23.x, w1, acc[2][1]);
            acc[2][2] = fmaf(a23.x, w2, acc[2][2]);
            acc[2][3] = fmaf(a23.x, w3, acc[2][3]);
            acc[3][0] = fmaf(a23.y, w0, acc[3][0]);
            acc[3][1] = fmaf(a23.y, w1, acc[3][1]);
            acc[3][2] = fmaf(a23.y, w2, acc[3][2]);
            acc[3][3] = fmaf(a23.y, w3, acc[3][3]);
        }

        // 64-lane reduce of 16 values; totals land in lanes 48..63 (row 3)
        float outv = 0.0f;
#pragma unroll
        for (int oo = 0; oo < 16; ++oo) {
            float v = acc[oo >> 2][oo & 3];
            v = dpp_add<0xB1,  0xf>(v);   // quad_perm xor1
            v = dpp_add<0x4E,  0xf>(v);   // quad_perm xor2
            v = dpp_add<0x141, 0xf>(v);   // row_half_mirror -> sum of 8
            v = dpp_add<0x140, 0xf>(v);   // row_mirror      -> sum of 16
            v = dpp_add<0x142, 0xa>(v);   // row_bcast15 -> rows 1,3
            v = dpp_add<0x143, 0xc>(v);   // row_bcast31 -> row 3 = total
            if (o == oo) outv = v;
        }

        if (o >= 0) {
            float pre = outv + ((const float*)xh_lds)[xh_i] + my_bias;
            float hv  = fast_tanh(pre);
            // publish FIRST (consumer-visible store leads the critical path)
            unsigned long long p = ((unsigned long long)(unsigned)t << 32)
                                 | (unsigned long long)__builtin_bit_cast(unsigned, hv);
            __hip_atomic_store(hbuf + ((size_t)(t & 1)) * HSLOT + (size_t)my_n * H_D + my_c,
                               p, __ATOMIC_RELAXED, __HIP_MEMORY_SCOPE_AGENT);
            out[((size_t)my_n * T_S + (t - 1)) * H_D + my_c] = hv;
            if (t == T_S)
                out[(size_t)N_B * T_S * H_D + (size_t)my_n * H_D + my_c] = hv;
        }
        __syncthreads();   // h2/xh_lds may be overwritten next step
    }
}

extern "C" void kernel_launch(void* const* d_in, const int* in_sizes, int n_in,
                              void* d_out, int out_size, void* d_ws, size_t ws_size,
                              hipStream_t stream) {
    const int*   xx    = (const int*)d_in[0];
    const float* embed = (const float*)d_in[1];
    const float* W     = (const float*)d_in[2];
    const float* bh    = (const float*)d_in[3];
    float* out = (float*)d_out;
    unsigned long long* hbuf = (unsigned long long*)d_ws;

    // clear tags in BOTH parity slots each call (kills cross-replay stale-tag match)
    hipMemsetAsync(d_ws, 0, 2 * HSLOT * sizeof(unsigned long long), stream);

    void* args[] = { (void*)&xx, (void*)&embed, (void*)&W, (void*)&bh,
                     (void*)&out, (void*)&hbuf };
    hipLaunchCooperativeKernel((const void*)rnn_persist, dim3(256), dim3(512),
                               args, 0, stream);
}